// Round 1
// baseline (571.076 us; speedup 1.0000x reference)
//
#include <hip/hip_runtime.h>

#define N_NODES 10000
#define N_EDGES 640000
#define IN_CH   512
#define H       7

// deg[i] starts at 1.0 (self-loop weight); accumulators seeded with bias so
// the final scatter-add lands directly on out = segsum + b.
__global__ void k_init(float* deg, float* out1, float* dout,
                       const float* __restrict__ b1, const float* __restrict__ b2) {
    int i = blockIdx.x * blockDim.x + threadIdx.x;
    if (i < N_NODES) deg[i] = 1.0f;
    if (i < N_NODES * H) {
        out1[i] = b1[i % H];
        dout[i] = b2[i % H];
    }
    if (i == N_NODES * H) dout[i] = 0.0f;   // reg output
}

__global__ void k_deg(const int* __restrict__ row, const float* __restrict__ ew,
                      float* deg) {
    int e = blockIdx.x * blockDim.x + threadIdx.x;
    if (e < N_EDGES) atomicAdd(&deg[row[e]], ew[e]);
}

__global__ void k_deginv(float* deg) {
    int i = blockIdx.x * blockDim.x + threadIdx.x;
    if (i < N_NODES) {
        float d = deg[i];
        deg[i] = d > 0.0f ? rsqrtf(d) : 0.0f;   // in-place: deg -> deg^-1/2
    }
}

// h1 = x @ W1 : one wave per node row. W1 (512x7 = 14KB) staged in LDS.
// Lane l reads x[row][t+l] (coalesced 256B/instr); LDS reads stride-7
// (7 coprime 32 -> 2-way aliasing, free on CDNA4).
__global__ __launch_bounds__(256) void k_mm1(const float* __restrict__ x,
                                             const float* __restrict__ W1,
                                             float* __restrict__ h1) {
    __shared__ float w[IN_CH * H];
    for (int i = threadIdx.x; i < IN_CH * H; i += 256) w[i] = W1[i];
    __syncthreads();
    int wave = threadIdx.x >> 6;
    int lane = threadIdx.x & 63;
    int row  = blockIdx.x * 4 + wave;
    if (row >= N_NODES) return;
    const float* xr = x + (size_t)row * IN_CH;
    float acc[H] = {};
    for (int t = 0; t < IN_CH; t += 64) {
        float xv = xr[t + lane];
        const float* wk = &w[(t + lane) * H];
        #pragma unroll
        for (int c = 0; c < H; ++c) acc[c] += xv * wk[c];
    }
    #pragma unroll
    for (int c = 0; c < H; ++c) {
        float v = acc[c];
        #pragma unroll
        for (int off = 32; off; off >>= 1) v += __shfl_xor(v, off);
        if (lane == 0) h1[row * H + c] = v;
    }
}

// Edge scatter: out[row] += dinv[row]*ew*dinv[col] * h[col]; tail threads do
// the N self-loops (w = dinv[i]^2). out must be pre-seeded with bias.
__global__ void k_agg(const int* __restrict__ row, const int* __restrict__ col,
                      const float* __restrict__ ew, const float* __restrict__ dinv,
                      const float* __restrict__ h, float* out) {
    int e = blockIdx.x * blockDim.x + threadIdx.x;
    if (e < N_EDGES) {
        int r = row[e], c = col[e];
        float wgt = dinv[r] * ew[e] * dinv[c];
        const float* hc = h + c * H;
        float* orow = out + r * H;
        #pragma unroll
        for (int j = 0; j < H; ++j) atomicAdd(&orow[j], wgt * hc[j]);
    } else {
        int i = e - N_EDGES;
        if (i < N_NODES) {
            float wgt = dinv[i] * dinv[i];
            const float* hc = h + i * H;
            float* orow = out + i * H;
            #pragma unroll
            for (int j = 0; j < H; ++j) atomicAdd(&orow[j], wgt * hc[j]);
        }
    }
}

// h2 = (out1) @ W2  (out1 already includes b1). 7x7 weights in LDS.
__global__ void k_mm2(const float* __restrict__ in, const float* __restrict__ W2,
                      float* __restrict__ h2) {
    __shared__ float w[H * H];
    if (threadIdx.x < H * H) w[threadIdx.x] = W2[threadIdx.x];
    __syncthreads();
    int i = blockIdx.x * blockDim.x + threadIdx.x;
    if (i >= N_NODES) return;
    float v[H];
    #pragma unroll
    for (int k = 0; k < H; ++k) v[k] = in[i * H + k];
    #pragma unroll
    for (int c = 0; c < H; ++c) {
        float a = 0.0f;
        #pragma unroll
        for (int k = 0; k < H; ++k) a += v[k] * w[k * H + c];
        h2[i * H + c] = a;
    }
}

extern "C" void kernel_launch(void* const* d_in, const int* in_sizes, int n_in,
                              void* d_out, int out_size, void* d_ws, size_t ws_size,
                              hipStream_t stream) {
    const float* x  = (const float*)d_in[0];
    const int*   ei = (const int*)d_in[1];
    const float* ea = (const float*)d_in[2];
    // d_in[3] = adj, unused
    const float* W1 = (const float*)d_in[4];
    const float* b1 = (const float*)d_in[5];
    const float* W2 = (const float*)d_in[6];
    const float* b2 = (const float*)d_in[7];
    float* out = (float*)d_out;

    float* deg  = (float*)d_ws;           // N floats (becomes deg_inv)
    float* h1   = deg  + N_NODES;         // N*H
    float* out1 = h1   + N_NODES * H;     // N*H
    float* h2   = out1 + N_NODES * H;     // N*H

    const int* row = ei;
    const int* col = ei + N_EDGES;

    k_init<<<(N_NODES * H + 1 + 255) / 256, 256, 0, stream>>>(deg, out1, out, b1, b2);
    k_deg<<<(N_EDGES + 255) / 256, 256, 0, stream>>>(row, ea, deg);
    k_deginv<<<(N_NODES + 255) / 256, 256, 0, stream>>>(deg);
    k_mm1<<<(N_NODES + 3) / 4, 256, 0, stream>>>(x, W1, h1);
    k_agg<<<(N_EDGES + N_NODES + 255) / 256, 256, 0, stream>>>(row, col, ea, deg, h1, out1);
    k_mm2<<<(N_NODES + 255) / 256, 256, 0, stream>>>(out1, W2, h2);
    k_agg<<<(N_EDGES + N_NODES + 255) / 256, 256, 0, stream>>>(row, col, ea, deg, h2, out);
}

// Round 2
// 169.978 us; speedup vs baseline: 3.3597x; 3.3597x over previous
//
#include <hip/hip_runtime.h>

#define N_NODES 10000
#define N_EDGES 640000
#define IN_CH   512
#define H       7

__device__ inline float wave_sum(float v) {
    #pragma unroll
    for (int off = 32; off; off >>= 1) v += __shfl_xor(v, off);
    return v;
}

// deg=1 (self-loop), cnt=0, reg output element = 0.
__global__ void k_setup(float* deg, int* cnt, float* dout) {
    int i = blockIdx.x * blockDim.x + threadIdx.x;
    if (i < N_NODES) { deg[i] = 1.0f; cnt[i] = 0; }
    if (i == 0) dout[N_NODES * H] = 0.0f;   // reg
}

// Fused: deg[r] += ew, cnt[r]++ per edge.
__global__ void k_deg_count(const int* __restrict__ row, const float* __restrict__ ew,
                            float* deg, int* cnt) {
    int e = blockIdx.x * blockDim.x + threadIdx.x;
    if (e < N_EDGES) {
        int r = row[e];
        atomicAdd(&deg[r], ew[e]);
        atomicAdd(&cnt[r], 1);
    }
}

__global__ void k_deginv(float* deg) {
    int i = blockIdx.x * blockDim.x + threadIdx.x;
    if (i < N_NODES) deg[i] = rsqrtf(deg[i]);   // deg >= 1 always (self-loop)
}

// Exclusive prefix scan of cnt[0..N) -> rowptr, cursor. One 1024-thread block.
__global__ __launch_bounds__(1024) void k_scan(const int* __restrict__ cnt,
                                               int* rowptr, int* cursor) {
    __shared__ int wsum[16];
    __shared__ int carry_s;
    int tid = threadIdx.x, lane = tid & 63, wave = tid >> 6;
    if (tid == 0) carry_s = 0;
    __syncthreads();
    for (int base = 0; base < N_NODES; base += 1024) {
        int i = base + tid;
        int v = (i < N_NODES) ? cnt[i] : 0;
        int s = v;
        #pragma unroll
        for (int off = 1; off < 64; off <<= 1) {
            int t = __shfl_up(s, off);
            if (lane >= off) s += t;
        }
        if (lane == 63) wsum[wave] = s;
        __syncthreads();
        if (tid == 0) {                      // serial scan of 16 wave totals
            int run = carry_s;
            #pragma unroll
            for (int k = 0; k < 16; ++k) { int t = wsum[k]; wsum[k] = run; run += t; }
            carry_s = run;
        }
        __syncthreads();
        int excl = wsum[wave] + s - v;
        if (i < N_NODES) { rowptr[i] = excl; cursor[i] = excl; }
        __syncthreads();                     // wsum reused next iteration
    }
}

// Counting-sort scatter; stores col and fully-normalized edge weight.
__global__ void k_scatter(const int* __restrict__ row, const int* __restrict__ col,
                          const float* __restrict__ ew, const float* __restrict__ dinv,
                          int* cursor, int* scol, float* sw) {
    int e = blockIdx.x * blockDim.x + threadIdx.x;
    if (e < N_EDGES) {
        int r = row[e], c = col[e];
        float w = dinv[r] * ew[e] * dinv[c];
        int pos = atomicAdd(&cursor[r], 1);
        scol[pos] = c;
        sw[pos] = w;
    }
}

// h1 = x @ W1 : one wave per node row, W1 (14KB) in LDS.
__global__ __launch_bounds__(256) void k_mm1(const float* __restrict__ x,
                                             const float* __restrict__ W1,
                                             float* __restrict__ h1) {
    __shared__ float w[IN_CH * H];
    for (int i = threadIdx.x; i < IN_CH * H; i += 256) w[i] = W1[i];
    __syncthreads();
    int wave = threadIdx.x >> 6, lane = threadIdx.x & 63;
    int row = blockIdx.x * 4 + wave;
    if (row >= N_NODES) return;
    const float* xr = x + (size_t)row * IN_CH;
    float acc[H] = {};
    for (int t = 0; t < IN_CH; t += 64) {
        float xv = xr[t + lane];
        const float* wk = &w[(t + lane) * H];
        #pragma unroll
        for (int c = 0; c < H; ++c) acc[c] += xv * wk[c];
    }
    #pragma unroll
    for (int c = 0; c < H; ++c) {
        float v = wave_sum(acc[c]);
        if (lane == 0) h1[row * H + c] = v;
    }
}

// Gather aggregation: one wave per node, no atomics.
// out[n][:] = sum_e w_e * h[col_e][:] + dinv[n]^2 * h[n][:] + b[:]
__global__ __launch_bounds__(256) void k_gather(const int* __restrict__ rowptr,
                                                const int* __restrict__ cnt,
                                                const int* __restrict__ scol,
                                                const float* __restrict__ sw,
                                                const float* __restrict__ dinv,
                                                const float* __restrict__ h,
                                                const float* __restrict__ b,
                                                float* __restrict__ out) {
    int wave = threadIdx.x >> 6, lane = threadIdx.x & 63;
    int node = blockIdx.x * 4 + wave;
    if (node >= N_NODES) return;
    int start = rowptr[node], m = cnt[node];
    float acc[H] = {};
    for (int k = lane; k < m; k += 64) {
        int c = scol[start + k];
        float w = sw[start + k];
        const float* hc = h + c * H;
        #pragma unroll
        for (int j = 0; j < H; ++j) acc[j] += w * hc[j];
    }
    #pragma unroll
    for (int j = 0; j < H; ++j) acc[j] = wave_sum(acc[j]);
    if (lane == 0) {
        float di = dinv[node], self = di * di;
        const float* hn = h + node * H;
        float* orow = out + node * H;
        #pragma unroll
        for (int j = 0; j < H; ++j) orow[j] = acc[j] + self * hn[j] + b[j];
    }
}

// h2 = out1 @ W2 (7x7 weights in LDS).
__global__ void k_mm2(const float* __restrict__ in, const float* __restrict__ W2,
                      float* __restrict__ h2) {
    __shared__ float w[H * H];
    if (threadIdx.x < H * H) w[threadIdx.x] = W2[threadIdx.x];
    __syncthreads();
    int i = blockIdx.x * blockDim.x + threadIdx.x;
    if (i >= N_NODES) return;
    float v[H];
    #pragma unroll
    for (int k = 0; k < H; ++k) v[k] = in[i * H + k];
    #pragma unroll
    for (int c = 0; c < H; ++c) {
        float a = 0.0f;
        #pragma unroll
        for (int k = 0; k < H; ++k) a += v[k] * w[k * H + c];
        h2[i * H + c] = a;
    }
}

extern "C" void kernel_launch(void* const* d_in, const int* in_sizes, int n_in,
                              void* d_out, int out_size, void* d_ws, size_t ws_size,
                              hipStream_t stream) {
    const float* x  = (const float*)d_in[0];
    const int*   ei = (const int*)d_in[1];
    const float* ea = (const float*)d_in[2];
    const float* W1 = (const float*)d_in[4];
    const float* b1 = (const float*)d_in[5];
    const float* W2 = (const float*)d_in[6];
    const float* b2 = (const float*)d_in[7];
    float* out = (float*)d_out;

    float* deg    = (float*)d_ws;                  // N  (becomes dinv)
    int*   cnt    = (int*)(deg + N_NODES);         // N
    int*   rowptr = cnt + N_NODES;                 // N
    int*   cursor = rowptr + N_NODES;              // N
    int*   scol   = cursor + N_NODES;              // E
    float* sw     = (float*)(scol + N_EDGES);      // E
    float* h1     = sw + N_EDGES;                  // N*H
    float* out1   = h1 + N_NODES * H;              // N*H
    float* h2     = out1 + N_NODES * H;            // N*H

    const int* row = ei;
    const int* col = ei + N_EDGES;

    k_setup<<<(N_NODES + 255) / 256, 256, 0, stream>>>(deg, cnt, out);
    k_deg_count<<<(N_EDGES + 255) / 256, 256, 0, stream>>>(row, ea, deg, cnt);
    k_deginv<<<(N_NODES + 255) / 256, 256, 0, stream>>>(deg);
    k_scan<<<1, 1024, 0, stream>>>(cnt, rowptr, cursor);
    k_scatter<<<(N_EDGES + 255) / 256, 256, 0, stream>>>(row, col, ea, deg, cursor, scol, sw);
    k_mm1<<<(N_NODES + 3) / 4, 256, 0, stream>>>(x, W1, h1);
    k_gather<<<(N_NODES + 3) / 4, 256, 0, stream>>>(rowptr, cnt, scol, sw, deg, h1, b1, out1);
    k_mm2<<<(N_NODES + 255) / 256, 256, 0, stream>>>(out1, W2, h2);
    k_gather<<<(N_NODES + 3) / 4, 256, 0, stream>>>(rowptr, cnt, scol, sw, deg, h2, b2, out);
}

// Round 3
// 107.095 us; speedup vs baseline: 5.3324x; 1.5872x over previous
//
#include <hip/hip_runtime.h>

#define N_NODES 10000
#define N_EDGES 640000
#define IN_CH   512
#define H       7
#define HB      64
#define CHUNK   (N_EDGES / HB)   // 10000 exactly

__device__ inline float wave_sum(float v) {
    #pragma unroll
    for (int off = 32; off; off >>= 1) v += __shfl_xor(v, off);
    return v;
}

// Per-block LDS histogram (counts) + partial degree sums. 64 blocks, each owns
// a 10k-edge chunk; the same 40 KB LDS buffer is reused int->float.
__global__ __launch_bounds__(256) void k_hist(const int* __restrict__ row,
                                              const float* __restrict__ ew,
                                              int* __restrict__ ghist,
                                              float* __restrict__ gdeg) {
    __shared__ int lh[N_NODES];
    int base = blockIdx.x * CHUNK;
    for (int i = threadIdx.x; i < N_NODES; i += 256) lh[i] = 0;
    __syncthreads();
    for (int i = threadIdx.x; i < CHUNK; i += 256)
        atomicAdd(&lh[row[base + i]], 1);
    __syncthreads();
    int* gh = ghist + blockIdx.x * N_NODES;
    for (int i = threadIdx.x; i < N_NODES; i += 256) gh[i] = lh[i];
    __syncthreads();
    float* lf = (float*)lh;                 // reuse LDS as float accumulators
    for (int i = threadIdx.x; i < N_NODES; i += 256) lf[i] = 0.0f;
    __syncthreads();
    for (int i = threadIdx.x; i < CHUNK; i += 256)
        atomicAdd(&lf[row[base + i]], ew[base + i]);
    __syncthreads();
    float* gd = gdeg + blockIdx.x * N_NODES;
    for (int i = threadIdx.x; i < N_NODES; i += 256) gd[i] = lf[i];
}

// Per-node column scan over the 64 per-block partials: ghist[b][i] becomes the
// exclusive within-node offset of block b, cnt[i] = node degree count,
// dinv[i] = (1 + sum ew)^-1/2. Also zeroes the reg output element.
__global__ void k_colscan(int* __restrict__ ghist, const float* __restrict__ gdeg,
                          int* __restrict__ cnt, float* __restrict__ dinv,
                          float* __restrict__ dout) {
    int i = blockIdx.x * blockDim.x + threadIdx.x;
    if (i == 0) dout[N_NODES * H] = 0.0f;
    if (i >= N_NODES) return;
    int run = 0;
    float ds = 1.0f;                         // self-loop weight
    #pragma unroll 4
    for (int b = 0; b < HB; ++b) {
        int v = ghist[b * N_NODES + i];
        ghist[b * N_NODES + i] = run;
        run += v;
        ds += gdeg[b * N_NODES + i];
    }
    cnt[i] = run;
    dinv[i] = rsqrtf(ds);
}

// Exclusive prefix scan cnt[0..N) -> rowptr[0..N]. One 1024-thread block.
__global__ __launch_bounds__(1024) void k_scan(const int* __restrict__ cnt,
                                               int* rowptr) {
    __shared__ int wsum[16];
    __shared__ int carry_s;
    int tid = threadIdx.x, lane = tid & 63, wave = tid >> 6;
    if (tid == 0) carry_s = 0;
    __syncthreads();
    for (int base = 0; base < N_NODES; base += 1024) {
        int i = base + tid;
        int v = (i < N_NODES) ? cnt[i] : 0;
        int s = v;
        #pragma unroll
        for (int off = 1; off < 64; off <<= 1) {
            int t = __shfl_up(s, off);
            if (lane >= off) s += t;
        }
        if (lane == 63) wsum[wave] = s;
        __syncthreads();
        if (tid == 0) {
            int run = carry_s;
            #pragma unroll
            for (int k = 0; k < 16; ++k) { int t = wsum[k]; wsum[k] = run; run += t; }
            carry_s = run;
        }
        __syncthreads();
        int excl = wsum[wave] + s - v;
        if (i < N_NODES) rowptr[i] = excl;
        __syncthreads();
    }
    if (tid == 0) rowptr[N_NODES] = carry_s;   // == N_EDGES
}

// Counting-sort scatter with LDS cursors (zero global atomics). Stores packed
// {col, ew*dinv[col]} per edge, sorted by row.
__global__ __launch_bounds__(256) void k_scatter(const int* __restrict__ row,
                                                 const int* __restrict__ col,
                                                 const float* __restrict__ ew,
                                                 const float* __restrict__ dinv,
                                                 const int* __restrict__ rowptr,
                                                 const int* __restrict__ ghist,
                                                 int2* __restrict__ sedge) {
    __shared__ int cur[N_NODES];
    const int* gh = ghist + blockIdx.x * N_NODES;
    for (int i = threadIdx.x; i < N_NODES; i += 256) cur[i] = rowptr[i] + gh[i];
    __syncthreads();
    int base = blockIdx.x * CHUNK;
    for (int i = threadIdx.x; i < CHUNK; i += 256) {
        int e = base + i;
        int r = row[e], c = col[e];
        float w = ew[e] * dinv[c];
        int pos = atomicAdd(&cur[r], 1);     // LDS atomic
        sedge[pos] = make_int2(c, __float_as_int(w));
    }
}

// h1 = x @ W1 : one wave per node row, W1 (14KB) in LDS.
__global__ __launch_bounds__(256) void k_mm1(const float* __restrict__ x,
                                             const float* __restrict__ W1,
                                             float* __restrict__ h1) {
    __shared__ float w[IN_CH * H];
    for (int i = threadIdx.x; i < IN_CH * H; i += 256) w[i] = W1[i];
    __syncthreads();
    int wave = threadIdx.x >> 6, lane = threadIdx.x & 63;
    int r = blockIdx.x * 4 + wave;
    if (r >= N_NODES) return;
    const float* xr = x + (size_t)r * IN_CH;
    float acc[H] = {};
    for (int t = 0; t < IN_CH; t += 64) {
        float xv = xr[t + lane];
        const float* wk = &w[(t + lane) * H];
        #pragma unroll
        for (int c = 0; c < H; ++c) acc[c] += xv * wk[c];
    }
    #pragma unroll
    for (int c = 0; c < H; ++c) {
        float v = wave_sum(acc[c]);
        if (lane == 0) h1[r * H + c] = v;
    }
}

// Gather aggregation, one wave per node:
//   res = dinv[n]*sum_k w_k*h[c_k] + dinv[n]^2*h[n] + bias      (w_k = ew*dinv[c])
// FUSE_MM2: additionally out = res @ W2 (lanes 0..6 each produce one column).
template <bool FUSE_MM2>
__global__ __launch_bounds__(256) void k_gather(const int* __restrict__ rowptr,
                                                const int2* __restrict__ sedge,
                                                const float* __restrict__ dinv,
                                                const float* __restrict__ h,
                                                const float* __restrict__ bias,
                                                const float* __restrict__ W2,
                                                float* __restrict__ out) {
    __shared__ float w2[H * H];
    if (FUSE_MM2) {
        if (threadIdx.x < H * H) w2[threadIdx.x] = W2[threadIdx.x];
        __syncthreads();
    }
    int wave = threadIdx.x >> 6, lane = threadIdx.x & 63;
    int node = blockIdx.x * 4 + wave;
    if (node >= N_NODES) return;
    int start = rowptr[node], end = rowptr[node + 1];
    float acc[H] = {};
    for (int k = start + lane; k < end; k += 64) {
        int2 e = sedge[k];
        float w = __int_as_float(e.y);
        const float* hc = h + e.x * H;
        #pragma unroll
        for (int j = 0; j < H; ++j) acc[j] += w * hc[j];
    }
    float di = dinv[node], self = di * di;
    const float* hn = h + node * H;
    float v[H];
    #pragma unroll
    for (int j = 0; j < H; ++j)
        v[j] = di * wave_sum(acc[j]) + self * hn[j] + bias[j];
    if (FUSE_MM2) {
        if (lane < H) {
            float a = 0.0f;
            #pragma unroll
            for (int k = 0; k < H; ++k) a += v[k] * w2[k * H + lane];
            out[node * H + lane] = a;
        }
    } else {
        if (lane < H) out[node * H + lane] = v[lane];
    }
}

extern "C" void kernel_launch(void* const* d_in, const int* in_sizes, int n_in,
                              void* d_out, int out_size, void* d_ws, size_t ws_size,
                              hipStream_t stream) {
    const float* x  = (const float*)d_in[0];
    const int*   ei = (const int*)d_in[1];
    const float* ea = (const float*)d_in[2];
    const float* W1 = (const float*)d_in[4];
    const float* b1 = (const float*)d_in[5];
    const float* W2 = (const float*)d_in[6];
    const float* b2 = (const float*)d_in[7];
    float* out = (float*)d_out;

    int*   ghist  = (int*)d_ws;                       // HB*N
    float* gdeg   = (float*)(ghist + HB * N_NODES);   // HB*N
    int*   cnt    = (int*)(gdeg + HB * N_NODES);      // N
    int*   rowptr = cnt + N_NODES;                    // N+1 (+1 pad)
    float* dinv   = (float*)(rowptr + N_NODES + 2);   // N
    int2*  sedge  = (int2*)(dinv + N_NODES);          // E (8B aligned)
    float* h1     = (float*)(sedge + N_EDGES);        // N*H
    float* h2     = h1 + N_NODES * H;                 // N*H

    const int* row = ei;
    const int* col = ei + N_EDGES;

    k_hist<<<HB, 256, 0, stream>>>(row, ea, ghist, gdeg);
    k_colscan<<<(N_NODES + 255) / 256, 256, 0, stream>>>(ghist, gdeg, cnt, dinv, out);
    k_scan<<<1, 1024, 0, stream>>>(cnt, rowptr);
    k_scatter<<<HB, 256, 0, stream>>>(row, col, ea, dinv, rowptr, ghist, sedge);
    k_mm1<<<(N_NODES + 3) / 4, 256, 0, stream>>>(x, W1, h1);
    k_gather<true><<<(N_NODES + 3) / 4, 256, 0, stream>>>(rowptr, sedge, dinv, h1, b1, W2, h2);
    k_gather<false><<<(N_NODES + 3) / 4, 256, 0, stream>>>(rowptr, sedge, dinv, h2, b2, nullptr, out);
}

// Round 4
// 87.435 us; speedup vs baseline: 6.5314x; 1.2249x over previous
//
#include <hip/hip_runtime.h>

#define N_NODES 10000
#define N_EDGES 640000
#define IN_CH   512
#define H       7
#define HB      64
#define CHUNK   (N_EDGES / HB)          // 10000
#define MMROWS  16                      // rows per mm1 block (16 waves)
#define MMBLK   ((N_NODES + MMROWS - 1) / MMROWS)   // 625

__device__ inline float wave_sum(float v) {
    #pragma unroll
    for (int off = 32; off; off >>= 1) v += __shfl_xor(v, off);
    return v;
}

// Fused kernel: blocks [0,HB) build per-chunk LDS histograms (edge counts +
// partial ew sums); blocks [HB, HB+MMBLK) compute h1 = x @ W1 (W1 in LDS).
// The two branches share the same 40KB LDS buffer.
__global__ __launch_bounds__(1024) void k_hist_mm1(const int* __restrict__ row,
                                                   const float* __restrict__ ew,
                                                   const float* __restrict__ x,
                                                   const float* __restrict__ W1,
                                                   int* __restrict__ ghist,
                                                   float* __restrict__ gdeg,
                                                   float* __restrict__ h1) {
    __shared__ int lh[N_NODES];          // 40 KB, reused as float
    int tid = threadIdx.x;
    if (blockIdx.x < HB) {
        int b = blockIdx.x, base = b * CHUNK;
        for (int i = tid; i < N_NODES; i += 1024) lh[i] = 0;
        __syncthreads();
        for (int i = tid; i < CHUNK; i += 1024) atomicAdd(&lh[row[base + i]], 1);
        __syncthreads();
        int* gh = ghist + b * N_NODES;
        for (int i = tid; i < N_NODES; i += 1024) gh[i] = lh[i];
        __syncthreads();
        float* lf = (float*)lh;
        for (int i = tid; i < N_NODES; i += 1024) lf[i] = 0.0f;
        __syncthreads();
        for (int i = tid; i < CHUNK; i += 1024) atomicAdd(&lf[row[base + i]], ew[base + i]);
        __syncthreads();
        float* gd = gdeg + b * N_NODES;
        for (int i = tid; i < N_NODES; i += 1024) gd[i] = lf[i];
    } else {
        float* w = (float*)lh;           // 3584 floats of W1
        for (int i = tid; i < IN_CH * H; i += 1024) w[i] = W1[i];
        __syncthreads();
        int wave = tid >> 6, lane = tid & 63;
        int r = (blockIdx.x - HB) * MMROWS + wave;
        if (r >= N_NODES) return;
        const float* xr = x + (size_t)r * IN_CH;
        float acc[H] = {};
        for (int t = 0; t < IN_CH; t += 64) {
            float xv = xr[t + lane];
            const float* wk = &w[(t + lane) * H];
            #pragma unroll
            for (int c = 0; c < H; ++c) acc[c] += xv * wk[c];
        }
        #pragma unroll
        for (int c = 0; c < H; ++c) {
            float v = wave_sum(acc[c]);
            if (lane == 0) h1[r * H + c] = v;
        }
    }
}

// Per-node column scan over HB per-block partials: ghist[b][i] -> exclusive
// within-node offset; cnt[i] = degree count; dinv[i] = (1+sum ew)^-1/2.
__global__ __launch_bounds__(1024) void k_colscan(int* __restrict__ ghist,
                                                  const float* __restrict__ gdeg,
                                                  int* __restrict__ cnt,
                                                  float* __restrict__ dinv,
                                                  float* __restrict__ dout) {
    int i = blockIdx.x * blockDim.x + threadIdx.x;
    if (i == 0) dout[N_NODES * H] = 0.0f;   // reg output
    if (i >= N_NODES) return;
    int run = 0;
    float ds = 1.0f;                         // self-loop weight
    #pragma unroll 4
    for (int b = 0; b < HB; ++b) {
        int v = ghist[b * N_NODES + i];
        ghist[b * N_NODES + i] = run;
        run += v;
        ds += gdeg[b * N_NODES + i];
    }
    cnt[i] = run;
    dinv[i] = rsqrtf(ds);
}

// Exclusive prefix scan cnt[0..N) -> rowptr[0..N]. One 1024-thread block.
__global__ __launch_bounds__(1024) void k_scan(const int* __restrict__ cnt,
                                               int* rowptr) {
    __shared__ int wsum[16];
    __shared__ int carry_s;
    int tid = threadIdx.x, lane = tid & 63, wave = tid >> 6;
    if (tid == 0) carry_s = 0;
    __syncthreads();
    for (int base = 0; base < N_NODES; base += 1024) {
        int i = base + tid;
        int v = (i < N_NODES) ? cnt[i] : 0;
        int s = v;
        #pragma unroll
        for (int off = 1; off < 64; off <<= 1) {
            int t = __shfl_up(s, off);
            if (lane >= off) s += t;
        }
        if (lane == 63) wsum[wave] = s;
        __syncthreads();
        if (tid == 0) {
            int run = carry_s;
            #pragma unroll
            for (int k = 0; k < 16; ++k) { int t = wsum[k]; wsum[k] = run; run += t; }
            carry_s = run;
        }
        __syncthreads();
        int excl = wsum[wave] + s - v;
        if (i < N_NODES) rowptr[i] = excl;
        __syncthreads();
    }
    if (tid == 0) rowptr[N_NODES] = carry_s;
}

// Counting-sort scatter with LDS cursors (zero global atomics). Stores packed
// {col, ew*dinv[col]} per edge, sorted by row.
__global__ __launch_bounds__(1024) void k_scatter(const int* __restrict__ row,
                                                  const int* __restrict__ col,
                                                  const float* __restrict__ ew,
                                                  const float* __restrict__ dinv,
                                                  const int* __restrict__ rowptr,
                                                  const int* __restrict__ ghist,
                                                  int2* __restrict__ sedge) {
    __shared__ int cur[N_NODES];
    const int* gh = ghist + blockIdx.x * N_NODES;
    for (int i = threadIdx.x; i < N_NODES; i += 1024) cur[i] = rowptr[i] + gh[i];
    __syncthreads();
    int base = blockIdx.x * CHUNK;
    for (int i = threadIdx.x; i < CHUNK; i += 1024) {
        int e = base + i;
        int r = row[e], c = col[e];
        float w = ew[e] * dinv[c];
        int pos = atomicAdd(&cur[r], 1);     // LDS atomic
        sedge[pos] = make_int2(c, __float_as_int(w));
    }
}

// Gather aggregation, one wave per node:
//   res = dinv[n]*sum_k w_k*h[c_k] + dinv[n]^2*h[n] + bias
// FUSE_MM2: additionally out = res @ W2 (lanes 0..6 each produce one column).
template <bool FUSE_MM2>
__global__ __launch_bounds__(256) void k_gather(const int* __restrict__ rowptr,
                                                const int2* __restrict__ sedge,
                                                const float* __restrict__ dinv,
                                                const float* __restrict__ h,
                                                const float* __restrict__ bias,
                                                const float* __restrict__ W2,
                                                float* __restrict__ out) {
    __shared__ float w2[H * H];
    if (FUSE_MM2) {
        if (threadIdx.x < H * H) w2[threadIdx.x] = W2[threadIdx.x];
        __syncthreads();
    }
    int wave = threadIdx.x >> 6, lane = threadIdx.x & 63;
    int node = blockIdx.x * 4 + wave;
    if (node >= N_NODES) return;
    int start = rowptr[node], end = rowptr[node + 1];
    float acc[H] = {};
    for (int k = start + lane; k < end; k += 64) {
        int2 e = sedge[k];
        float w = __int_as_float(e.y);
        const float* hc = h + e.x * H;
        #pragma unroll
        for (int j = 0; j < H; ++j) acc[j] += w * hc[j];
    }
    float di = dinv[node], self = di * di;
    const float* hn = h + node * H;
    float v[H];
    #pragma unroll
    for (int j = 0; j < H; ++j)
        v[j] = di * wave_sum(acc[j]) + self * hn[j] + bias[j];
    if (FUSE_MM2) {
        if (lane < H) {
            float a = 0.0f;
            #pragma unroll
            for (int k = 0; k < H; ++k) a += v[k] * w2[k * H + lane];
            out[node * H + lane] = a;
        }
    } else {
        if (lane < H) out[node * H + lane] = v[lane];
    }
}

extern "C" void kernel_launch(void* const* d_in, const int* in_sizes, int n_in,
                              void* d_out, int out_size, void* d_ws, size_t ws_size,
                              hipStream_t stream) {
    const float* x  = (const float*)d_in[0];
    const int*   ei = (const int*)d_in[1];
    const float* ea = (const float*)d_in[2];
    const float* W1 = (const float*)d_in[4];
    const float* b1 = (const float*)d_in[5];
    const float* W2 = (const float*)d_in[6];
    const float* b2 = (const float*)d_in[7];
    float* out = (float*)d_out;

    int*   ghist  = (int*)d_ws;                       // HB*N
    float* gdeg   = (float*)(ghist + HB * N_NODES);   // HB*N
    int*   cnt    = (int*)(gdeg + HB * N_NODES);      // N
    int*   rowptr = cnt + N_NODES;                    // N+1 (+pad)
    float* dinv   = (float*)(rowptr + N_NODES + 2);   // N
    int2*  sedge  = (int2*)(dinv + N_NODES);          // E (8B aligned)
    float* h1     = (float*)(sedge + N_EDGES);        // N*H
    float* h2     = h1 + N_NODES * H;                 // N*H

    const int* row = ei;
    const int* col = ei + N_EDGES;

    k_hist_mm1<<<HB + MMBLK, 1024, 0, stream>>>(row, ea, x, W1, ghist, gdeg, h1);
    k_colscan<<<(N_NODES + 1023) / 1024, 1024, 0, stream>>>(ghist, gdeg, cnt, dinv, out);
    k_scan<<<1, 1024, 0, stream>>>(cnt, rowptr);
    k_scatter<<<HB, 1024, 0, stream>>>(row, col, ea, dinv, rowptr, ghist, sedge);
    k_gather<true><<<(N_NODES + 3) / 4, 256, 0, stream>>>(rowptr, sedge, dinv, h1, b1, W2, h2);
    k_gather<false><<<(N_NODES + 3) / 4, 256, 0, stream>>>(rowptr, sedge, dinv, h2, b2, nullptr, out);
}